// Round 3
// baseline (130.276 us; speedup 1.0000x reference)
//
#include <hip/hip_runtime.h>
#include <hip/hip_bf16.h>

// CategorySpecificLinear: out[b,t,h] = sum_d x[b,t,d] * W[cat[b],d,h] + bias[cat[b],h]
// B=256, T=32, D=1024, H=1024, NCAT=32.
// R3: 3-deep pipeline (prefetch distance = 2 K-tiles, two named register sets,
// loop unrolled x2 so all vector indexing is static), double-buffered LDS,
// single raw s_barrier per K-step with lgkmcnt-only drain (prefetch loads ride
// across the barrier), XCD-chunked block swizzle.

#define NCAT 32
#define DIN  1024
#define DH   1024
#define NBATCH 256
#define TT   32
#define MAXREC 96

#define BM 128
#define BN 128
#define BK 32
#define LDK 40   // LDS row stride in bf16 elems (BK + 8 pad)
#define NITER (DIN / BK)   // 32 (even — unroll-by-2 safe)
#define NTILES (DH / BN)   // 8

typedef __attribute__((ext_vector_type(4))) float f32x4;
typedef __attribute__((ext_vector_type(8))) short bf16x8;
typedef __attribute__((ext_vector_type(4))) short bf16x4;

__device__ inline short f2bf(float f) {
    unsigned u = __builtin_bit_cast(unsigned, f);
    u += 0x7fffu + ((u >> 16) & 1u);
    return (short)(u >> 16);
}

// ---------------------------------------------------------------------------
// Setup: bucket batches by category into <=96 records {cat, nb, b0..b3, pad2}.
// ---------------------------------------------------------------------------
__global__ void cat_setup_kernel(const int* __restrict__ cat_ids,
                                 int* __restrict__ recs) {
    __shared__ int cats[NBATCH];
    __shared__ int offs[NCAT + 1];
    const int t = threadIdx.x;
    cats[t] = cat_ids[t];
    for (int i = t; i < MAXREC * 8; i += 256) recs[i] = 0;
    __syncthreads();
    if (t < NCAT) {
        int cnt = 0;
        for (int i = 0; i < NBATCH; ++i) cnt += (cats[i] == t) ? 1 : 0;
        offs[t + 1] = (cnt + 3) >> 2;
    }
    __syncthreads();
    if (t == 0) {
        offs[0] = 0;
        for (int c = 0; c < NCAT; ++c) offs[c + 1] += offs[c];
    }
    __syncthreads();
    if (t < NCAT) {
        int base = offs[t];
        int b0 = 0, b1 = 0, b2 = 0, b3 = 0;
        int nb = 0, k = 0;
        for (int i = 0; i < NBATCH; ++i) {
            if (cats[i] == t) {
                if (nb == 0) b0 = i; else if (nb == 1) b1 = i;
                else if (nb == 2) b2 = i; else b3 = i;
                ++nb;
                if (nb == 4) {
                    int* r = recs + (base + k) * 8;
                    r[0] = t; r[1] = 4; r[2] = b0; r[3] = b1; r[4] = b2; r[5] = b3;
                    ++k; nb = 0;
                }
            }
        }
        if (nb > 0) {
            int* r = recs + (base + k) * 8;
            r[0] = t; r[1] = nb;
            r[2] = b0;
            r[3] = (nb > 1) ? b1 : b0;
            r[4] = (nb > 2) ? b2 : b0;
            r[5] = (nb > 3) ? b3 : b0;
        }
    }
}

// One K-step: convert+stage tile `it` (waits its loads via reg dep), issue
// prefetch for tile it+2 into the same (just-freed) register set, barrier
// (lgkm-only drain), ds_read fragments, 16 MFMAs.
__device__ __forceinline__ void gemm_step(
    f32x4 (&xv)[4], f32x4 (&wv)[4],
    short* xd, short* wdb,
    const short* ap, const short* bp,
    const float* xsrc, const float* wsrc,
    int wn4, int wk4, int it,
    f32x4 (&acc)[4][4]) {

    // --- convert + LDS write of tile `it` ---
    bf16x8 p0, p1;
#pragma unroll
    for (int i = 0; i < 4; ++i) {
        p0[i]     = f2bf(xv[0][i]);
        p0[i + 4] = f2bf(xv[1][i]);
        p1[i]     = f2bf(xv[2][i]);
        p1[i + 4] = f2bf(xv[3][i]);
    }
    *(bf16x8*)(xd)     = p0;
    *(bf16x8*)(xd + 8) = p1;

#pragma unroll
    for (int j = 0; j < 4; ++j) {
        bf16x4 q;
        q[0] = f2bf(wv[0][j]);
        q[1] = f2bf(wv[1][j]);
        q[2] = f2bf(wv[2][j]);
        q[3] = f2bf(wv[3][j]);
        *(bf16x4*)(wdb + (wn4 + j) * LDK + wk4) = q;
    }

    // --- prefetch tile it+2 into the just-freed register set ---
    if (it + 2 < NITER) {
        const int k0 = (it + 2) * BK;
#pragma unroll
        for (int i = 0; i < 4; ++i)
            xv[i] = *(const f32x4*)(xsrc + k0 + i * 4);
#pragma unroll
        for (int i = 0; i < 4; ++i)
            wv[i] = *(const f32x4*)(wsrc + (size_t)(k0 + i) * DH);
    }

    // drain LDS writes only — prefetch loads stay in flight across the barrier
    asm volatile("s_waitcnt lgkmcnt(0)" ::: "memory");
    __builtin_amdgcn_s_barrier();
    asm volatile("" ::: "memory");

    // --- fragments + MFMA on tile `it` ---
    bf16x8 af[4], bfr[4];
#pragma unroll
    for (int mi = 0; mi < 4; ++mi)
        af[mi] = *(const bf16x8*)(ap + mi * 16 * LDK);
#pragma unroll
    for (int ni = 0; ni < 4; ++ni)
        bfr[ni] = *(const bf16x8*)(bp + ni * 16 * LDK);

#pragma unroll
    for (int mi = 0; mi < 4; ++mi)
#pragma unroll
        for (int ni = 0; ni < 4; ++ni)
            acc[mi][ni] = __builtin_amdgcn_mfma_f32_16x16x32_bf16(
                af[mi], bfr[ni], acc[mi][ni], 0, 0, 0);
    // no trailing barrier: next step writes the other buffer; buffer reuse two
    // steps ahead is ordered by the next barrier's preceding lgkmcnt(0).
}

// ---------------------------------------------------------------------------
// Grouped GEMM. 256 threads = 4 waves (2x2), wave tile 64x64.
// ---------------------------------------------------------------------------
__launch_bounds__(256, 2)
__global__ void cat_gemm_kernel(const float* __restrict__ x,
                                const float* __restrict__ W,
                                const float* __restrict__ bias,
                                const int* __restrict__ recs,
                                float* __restrict__ out) {
    // XCD-chunked swizzle: 768 blocks = 8 XCDs x 96.
    const int wg    = blockIdx.x;
    const int lin   = (wg & 7) * ((MAXREC * NTILES) / 8) + (wg >> 3);
    const int irec  = lin >> 3;
    const int ntile = lin & 7;

    const int* rec = recs + irec * 8;
    const int cat = rec[0];
    const int nb  = rec[1];
    if (nb == 0) return;
    const int n0 = ntile * BN;

    __shared__ short xs[2][BM * LDK];
    __shared__ short wt[2][BN * LDK];

    const int t    = threadIdx.x;
    const int lane = t & 63;
    const int wid  = t >> 6;
    const int wm   = wid >> 1;
    const int wn   = wid & 1;
    const int fl   = lane & 15;
    const int kb   = lane >> 4;

    // X staging: row xr = t>>1, 16 cols at xc0
    const int xr     = t >> 1;
    const int xc0    = (t & 1) * 16;
    const int xbatch = rec[2 + (xr >> 5)];
    const float* xsrc = x + (size_t)(xbatch * TT + (xr & 31)) * DIN + xc0;
    short* xdst0 = &xs[0][0] + xr * LDK + xc0;
    short* xdst1 = &xs[1][0] + xr * LDK + xc0;

    // W staging: k rows wk4..wk4+3, n cols wn4..wn4+3 (register 4x4 transpose)
    const int wk4 = (t & 7) * 4;
    const int wn4 = (t >> 3) * 4;
    const float* wsrc = W + (size_t)cat * (DIN * DH) + (size_t)wk4 * DH + n0 + wn4;

    // bias early (latency hidden under K loop)
    float bv[4];
#pragma unroll
    for (int ni = 0; ni < 4; ++ni)
        bv[ni] = bias[cat * DH + n0 + wn * 64 + ni * 16 + fl];

    f32x4 acc[4][4];
#pragma unroll
    for (int i = 0; i < 4; ++i)
#pragma unroll
        for (int j = 0; j < 4; ++j)
            acc[i][j] = (f32x4){0.f, 0.f, 0.f, 0.f};

    const short* ap0 = &xs[0][0] + (wm * 64 + fl) * LDK + kb * 8;
    const short* ap1 = &xs[1][0] + (wm * 64 + fl) * LDK + kb * 8;
    const short* bp0 = &wt[0][0] + (wn * 64 + fl) * LDK + kb * 8;
    const short* bp1 = &wt[1][0] + (wn * 64 + fl) * LDK + kb * 8;

    // prologue: load K-tiles 0 (set A) and 1 (set B)
    f32x4 xvA[4], wvA[4], xvB[4], wvB[4];
#pragma unroll
    for (int i = 0; i < 4; ++i) xvA[i] = *(const f32x4*)(xsrc + i * 4);
#pragma unroll
    for (int i = 0; i < 4; ++i) wvA[i] = *(const f32x4*)(wsrc + (size_t)i * DH);
#pragma unroll
    for (int i = 0; i < 4; ++i) xvB[i] = *(const f32x4*)(xsrc + BK + i * 4);
#pragma unroll
    for (int i = 0; i < 4; ++i) wvB[i] = *(const f32x4*)(wsrc + (size_t)(BK + i) * DH);

    for (int it = 0; it < NITER; it += 2) {
        gemm_step(xvA, wvA, xdst0, &wt[0][0], ap0, bp0, xsrc, wsrc, wn4, wk4, it,     acc);
        gemm_step(xvB, wvB, xdst1, &wt[1][0], ap1, bp1, xsrc, wsrc, wn4, wk4, it + 1, acc);
    }

    // --- epilogue: bias + store rows of real batches ---
#pragma unroll
    for (int mi = 0; mi < 4; ++mi) {
        const int slot = wm * 2 + (mi >> 1);
        if (slot < nb) {
            const int batch = rec[2 + slot];
            const int rbase = wm * 64 + mi * 16 + kb * 4;
#pragma unroll
            for (int j = 0; j < 4; ++j) {
                const int trow = (rbase + j) & 31;
                float* orow = out + (size_t)(batch * TT + trow) * DH + n0 + wn * 64;
#pragma unroll
                for (int ni = 0; ni < 4; ++ni)
                    orow[ni * 16 + fl] = acc[mi][ni][j] + bv[ni];
            }
        }
    }
}

extern "C" void kernel_launch(void* const* d_in, const int* in_sizes, int n_in,
                              void* d_out, int out_size, void* d_ws, size_t ws_size,
                              hipStream_t stream) {
    const float* x       = (const float*)d_in[0];
    const int*   cat_ids = (const int*)d_in[1];
    const float* W       = (const float*)d_in[2];
    const float* bias    = (const float*)d_in[3];
    float*       out     = (float*)d_out;
    int*         recs    = (int*)d_ws;

    hipLaunchKernelGGL(cat_setup_kernel, dim3(1), dim3(256), 0, stream,
                       cat_ids, recs);
    hipLaunchKernelGGL(cat_gemm_kernel, dim3(MAXREC * NTILES), dim3(256), 0, stream,
                       x, W, bias, recs, out);
}